// Round 7
// baseline (41.568 us; speedup 1.0000x reference)
//
#include <hip/hip_runtime.h>
#include <math.h>

// Problem constants (match reference)
#define VOCAB   100000
#define EMBED_D 128
#define BATCH_N 16384
#define CTX     8
#define NNEG    5

#define NBLOCKS 1024
#define TPB     256                     // 4 waves/block
#define WPB     (TPB / 64)
#define NWAVES  (NBLOCKS * WPB)         // 4096 waves
#define EPW     (BATCH_N / NWAVES)      // 4 elements per wave (blocked)

// Single fused kernel. Stage-1 body is byte-identical to round 3 (best: 29.6us).
// Cross-block handoff uses agent-scope relaxed atomics (sc1 stores/loads that
// BYPASS the non-coherent per-XCD L2) instead of round 4's catastrophic
// per-block __threadfence() L2-writeback storm. Ticket counter (integer,
// memset to 0 per call) elects the last block to reduce + epilogue.
__global__ __launch_bounds__(TPB) void cbow_fused_kernel(
    const int* __restrict__ pos_u,   // [B, C]
    const int* __restrict__ pos_w,   // [B]
    const int* __restrict__ neg_w,   // [B, NEG]
    const float* __restrict__ W,     // [VOCAB, D]
    float* __restrict__ partials,    // [6][NBLOCKS] in d_ws
    unsigned int* __restrict__ counter, // 1 uint in d_ws, zeroed per call
    float* __restrict__ out)
{
    const int lane = threadIdx.x & 63;
    const int wib  = threadIdx.x >> 6;
    const int g    = blockIdx.x * WPB + wib;

    const float2* __restrict__ W2 = (const float2*)W;   // 64 float2 per row

    float accs[6] = {0.f, 0.f, 0.f, 0.f, 0.f, 0.f};

    const int base = __builtin_amdgcn_readfirstlane(g * EPW);

    #pragma unroll
    for (int p = 0; p < EPW / 2; ++p) {
        const int e0 = base + 2 * p;
        const int e1 = e0 + 1;

        // ---- wave-uniform index loads (contiguous -> wide s_loads) ----
        int c0[CTX], c1[CTX];
        #pragma unroll
        for (int c = 0; c < CTX; ++c) {
            c0[c] = pos_u[e0 * CTX + c];
            c1[c] = pos_u[e1 * CTX + c];
        }
        const int ip0 = pos_w[e0];
        const int ip1 = pos_w[e1];
        int n0[NNEG], n1[NNEG];
        #pragma unroll
        for (int n = 0; n < NNEG; ++n) {
            n0[n] = neg_w[e0 * NNEG + n];
            n1[n] = neg_w[e1 * NNEG + n];
        }

        // ---- context-sum gathers for both elements (16 independent loads) ----
        float2 us0 = make_float2(0.f, 0.f);
        float2 us1 = make_float2(0.f, 0.f);
        #pragma unroll
        for (int c = 0; c < CTX; ++c) {
            const float2 a = W2[(size_t)c0[c] * (EMBED_D / 2) + lane];
            const float2 b = W2[(size_t)c1[c] * (EMBED_D / 2) + lane];
            us0.x += a.x; us0.y += a.y;
            us1.x += b.x; us1.y += b.y;
        }

        // ---- 12 target-row gathers + dot partials ----
        {
            const float2 a = W2[(size_t)ip0 * (EMBED_D / 2) + lane];
            const float2 b = W2[(size_t)ip1 * (EMBED_D / 2) + lane];
            accs[0] += us0.x * a.x + us0.y * a.y
                     + us1.x * b.x + us1.y * b.y;
        }
        #pragma unroll
        for (int n = 0; n < NNEG; ++n) {
            const float2 a = W2[(size_t)n0[n] * (EMBED_D / 2) + lane];
            const float2 b = W2[(size_t)n1[n] * (EMBED_D / 2) + lane];
            accs[1 + n] += us0.x * a.x + us0.y * a.y
                         + us1.x * b.x + us1.y * b.y;
        }
    }

    // ---- wave reduction of the 6 accumulators ----
    #pragma unroll
    for (int k = 0; k < 6; ++k) {
        float v = accs[k];
        #pragma unroll
        for (int off = 32; off > 0; off >>= 1)
            v += __shfl_down(v, off, 64);
        accs[k] = v;
    }

    __shared__ float sred[WPB][6];
    if (lane == 0) {
        #pragma unroll
        for (int k = 0; k < 6; ++k) sred[wib][k] = accs[k];
    }
    __syncthreads();

    if (threadIdx.x < 6) {
        float s = 0.f;
        #pragma unroll
        for (int w = 0; w < WPB; ++w) s += sred[w][threadIdx.x];
        // agent-scope write-through (sc1): bypasses this XCD's L2, lands at
        // the coherent point -> visible to the last block without any fence.
        __hip_atomic_store(&partials[threadIdx.x * NBLOCKS + blockIdx.x], s,
                           __ATOMIC_RELAXED, __HIP_MEMORY_SCOPE_AGENT);
    }

    // ---- ticket: last block to arrive does the final reduction ----
    __shared__ unsigned int tick;
    __syncthreads();   // compiler emits s_waitcnt vmcnt(0) before s_barrier:
                       // the partial stores are complete at the coherent point.
    if (threadIdx.x == 0) {
        tick = __hip_atomic_fetch_add(counter, 1u,
                                      __ATOMIC_RELAXED, __HIP_MEMORY_SCOPE_AGENT);
    }
    __syncthreads();

    if (tick == NBLOCKS - 1) {
        __shared__ float sv[6];
        for (int k = wib; k < 6; k += WPB) {   // waves take k={0,4},{1,5},{2},{3}
            float s = 0.f;
            for (int i = lane; i < NBLOCKS; i += 64)
                s += __hip_atomic_load(&partials[k * NBLOCKS + i],
                                       __ATOMIC_RELAXED, __HIP_MEMORY_SCOPE_AGENT);
            #pragma unroll
            for (int off = 32; off > 0; off >>= 1)
                s += __shfl_down(s, off, 64);
            if (lane == 0) sv[k] = s;
        }
        __syncthreads();

        if (threadIdx.x == 0) {
            // log_sigmoid(x) = min(x,0) - log1p(exp(-|x|))
            const float spos = sv[0];
            float loss = -(fminf(spos, 0.f) - log1pf(expf(-fabsf(spos))));
            #pragma unroll
            for (int k = 1; k < 6; ++k) {
                const float x = -sv[k];      // log_sigmoid(-s_neg)
                loss -= (fminf(x, 0.f) - log1pf(expf(-fabsf(x))));
            }
            out[0] = loss;
        }
    }
}

extern "C" void kernel_launch(void* const* d_in, const int* in_sizes, int n_in,
                              void* d_out, int out_size, void* d_ws, size_t ws_size,
                              hipStream_t stream) {
    const int*   pos_u = (const int*)d_in[0];
    const int*   pos_w = (const int*)d_in[1];
    const int*   neg_w = (const int*)d_in[2];
    const float* W     = (const float*)d_in[3];
    float* out = (float*)d_out;

    float* partials = (float*)d_ws;                       // 6*NBLOCKS floats = 24 KB
    unsigned int* counter = (unsigned int*)((char*)d_ws + 6 * NBLOCKS * sizeof(float));

    hipMemsetAsync(counter, 0, sizeof(unsigned int), stream);  // capture-safe
    cbow_fused_kernel<<<NBLOCKS, TPB, 0, stream>>>(pos_u, pos_w, neg_w, W,
                                                   partials, counter, out);
}

// Round 8
// 29.535 us; speedup vs baseline: 1.4074x; 1.4074x over previous
//
#include <hip/hip_runtime.h>
#include <math.h>

// Problem constants (match reference)
#define VOCAB   100000
#define EMBED_D 128
#define BATCH_N 16384
#define CTX     8
#define NNEG    5

#define NBLOCKS 1024
#define TPB     256                     // 4 waves/block
#define WPB     (TPB / 64)
#define NWAVES  (NBLOCKS * WPB)         // 4096 waves
#define EPW     (BATCH_N / NWAVES)      // 4 elements per wave (2 pairs)

// Stage 1, half-wave float4 gathers: one VMEM instruction fetches TWO
// embedding rows (lanes 0-31 -> element e0's row, lanes 32-63 -> e1's row,
// 16 B/lane = 1024 B/instr). Same bytes as round 3 in HALF the VMEM
// instructions — probes the per-CU outstanding-instruction cap.
// Pairs processed sequentially to keep VGPRs ~80 (1024 blocks = 4 blk/CU
// needs only 4 waves/SIMD, so <=128 VGPR is safe; no min-occupancy bound).
__global__ __launch_bounds__(TPB) void cbow_partial_kernel(
    const int* __restrict__ pos_u,   // [B, C]
    const int* __restrict__ pos_w,   // [B]
    const int* __restrict__ neg_w,   // [B, NEG]
    const float* __restrict__ W,     // [VOCAB, D]
    float* __restrict__ partials)    // [6][NBLOCKS]
{
    const int lane = threadIdx.x & 63;
    const int wib  = threadIdx.x >> 6;
    const int g    = blockIdx.x * WPB + wib;
    const int half = lane >> 5;          // 0: element e0, 1: element e1
    const int sl   = lane & 31;          // float4 slot within the 512 B row

    const float4* __restrict__ W4 = (const float4*)W;   // 32 float4 per row

    float accs[6] = {0.f, 0.f, 0.f, 0.f, 0.f, 0.f};

    const int base = __builtin_amdgcn_readfirstlane(g * EPW);

    #pragma unroll
    for (int p = 0; p < EPW / 2; ++p) {
        const int e0 = base + 2 * p;
        const int e1 = e0 + 1;

        // ---- wave-uniform index loads (contiguous -> wide s_loads) ----
        int c0[CTX], c1[CTX];
        #pragma unroll
        for (int c = 0; c < CTX; ++c) {
            c0[c] = pos_u[e0 * CTX + c];
            c1[c] = pos_u[e1 * CTX + c];
        }
        const int ip0 = pos_w[e0];
        const int ip1 = pos_w[e1];
        int n0[NNEG], n1[NNEG];
        #pragma unroll
        for (int n = 0; n < NNEG; ++n) {
            n0[n] = neg_w[e0 * NNEG + n];
            n1[n] = neg_w[e1 * NNEG + n];
        }

        // ---- 8 context gathers (each covers BOTH elements' rows) ----
        float4 us = make_float4(0.f, 0.f, 0.f, 0.f);
        #pragma unroll
        for (int c = 0; c < CTX; ++c) {
            const int idx = half ? c1[c] : c0[c];        // v_cndmask from SGPRs
            const float4 v = W4[(size_t)idx * (EMBED_D / 4) + sl];
            us.x += v.x; us.y += v.y; us.z += v.z; us.w += v.w;
        }

        // ---- 6 target gathers (two rows each) + dot partials ----
        {
            const int idx = half ? ip1 : ip0;
            const float4 t = W4[(size_t)idx * (EMBED_D / 4) + sl];
            accs[0] += us.x * t.x + us.y * t.y + us.z * t.z + us.w * t.w;
        }
        #pragma unroll
        for (int n = 0; n < NNEG; ++n) {
            const int idx = half ? n1[n] : n0[n];
            const float4 t = W4[(size_t)idx * (EMBED_D / 4) + sl];
            accs[1 + n] += us.x * t.x + us.y * t.y + us.z * t.z + us.w * t.w;
        }
    }

    // ---- wave reduction: shfl over all 64 lanes sums both halves ----
    #pragma unroll
    for (int k = 0; k < 6; ++k) {
        float v = accs[k];
        #pragma unroll
        for (int off = 32; off > 0; off >>= 1)
            v += __shfl_down(v, off, 64);
        accs[k] = v;
    }

    __shared__ float sred[WPB][6];
    if (lane == 0) {
        #pragma unroll
        for (int k = 0; k < 6; ++k) sred[wib][k] = accs[k];
    }
    __syncthreads();

    if (threadIdx.x < 6) {
        float s = 0.f;
        #pragma unroll
        for (int w = 0; w < WPB; ++w) s += sred[w][threadIdx.x];
        partials[threadIdx.x * NBLOCKS + blockIdx.x] = s;   // [k][block]
    }
}

// Stage 2: 6 waves; wave k reduces partials[k][*] coalesced; thread 0 epilogue.
__global__ __launch_bounds__(384) void cbow_final_kernel(
    const float* __restrict__ partials, float* __restrict__ out)
{
    const int wave = threadIdx.x >> 6;   // 0..5 -> k
    const int lane = threadIdx.x & 63;

    float s = 0.f;
    for (int i = lane; i < NBLOCKS; i += 64)
        s += partials[wave * NBLOCKS + i];
    #pragma unroll
    for (int off = 32; off > 0; off >>= 1)
        s += __shfl_down(s, off, 64);

    __shared__ float sv[6];
    if (lane == 0) sv[wave] = s;
    __syncthreads();

    if (threadIdx.x == 0) {
        // log_sigmoid(x) = min(x,0) - log1p(exp(-|x|))
        const float spos = sv[0];
        float loss = -(fminf(spos, 0.f) - log1pf(expf(-fabsf(spos))));
        #pragma unroll
        for (int k = 1; k < 6; ++k) {
            const float x = -sv[k];      // log_sigmoid(-s_neg)
            loss -= (fminf(x, 0.f) - log1pf(expf(-fabsf(x))));
        }
        out[0] = loss;
    }
}

extern "C" void kernel_launch(void* const* d_in, const int* in_sizes, int n_in,
                              void* d_out, int out_size, void* d_ws, size_t ws_size,
                              hipStream_t stream) {
    const int*   pos_u = (const int*)d_in[0];
    const int*   pos_w = (const int*)d_in[1];
    const int*   neg_w = (const int*)d_in[2];
    const float* W     = (const float*)d_in[3];
    float* out = (float*)d_out;
    float* partials = (float*)d_ws;   // 6*NBLOCKS floats = 24 KB

    cbow_partial_kernel<<<NBLOCKS, TPB, 0, stream>>>(pos_u, pos_w, neg_w, W, partials);
    cbow_final_kernel<<<1, 384, 0, stream>>>(partials, out);
}